// Round 3
// baseline (92.649 us; speedup 1.0000x reference)
//
#include <hip/hip_runtime.h>
#include <hip/hip_bf16.h>

// x (32768,3072) f32, W1 (32,3072), b1 (32), W2 (10,32), b2 (10)
// out: (32768,10) f32 = sigmoid(relu(x@W1^T+b1)@W2^T+b2)

typedef float  f32x4  __attribute__((ext_vector_type(4)));
typedef short  short8 __attribute__((ext_vector_type(8)));

#define IN_SIZE 3072
#define ROWB    (IN_SIZE * 4)     // 12288 bytes per x row
#define HIDDEN  32
#define OUTS    10
#define NSTAGE  24                // 24 stages x 512 B/row = full K
#define ABUF_SZ 32768             // 64 rows x 512 B
#define BBUF_SZ 8192              // 4 steps x 2 KB of B fragments

__device__ __forceinline__ unsigned short f2bf(float f) {
    return __builtin_bit_cast(unsigned short, __float2bfloat16(f));
}

__device__ __forceinline__ short8 cvt8(f32x4 a, f32x4 b) {
    short8 r;
    r[0] = (short)f2bf(a[0]); r[1] = (short)f2bf(a[1]);
    r[2] = (short)f2bf(a[2]); r[3] = (short)f2bf(a[3]);
    r[4] = (short)f2bf(b[0]); r[5] = (short)f2bf(b[1]);
    r[6] = (short)f2bf(b[2]); r[7] = (short)f2bf(b[3]);
    return r;
}

// Pre-swizzle W1 (32x3072 f32) into bf16 B-fragment layout:
// frag index t = s*128 + nt*64 + lane ; element j (0..7):
//   value = W1[(lane&15)+16*nt][ s*32 + (lane>>4)*8 + j ]
__global__ void prep_w1(const float* __restrict__ W1,
                        unsigned short* __restrict__ w1s) {
    int t  = blockIdx.x * 256 + threadIdx.x;      // 0..12287
    int l  = t & 63;
    int nt = (t >> 6) & 1;
    int s  = t >> 7;
    int h  = (l & 15) + nt * 16;
    int k  = s * 32 + ((l >> 4) * 8);
    const float* src = W1 + (size_t)h * IN_SIZE + k;
    f32x4 f0 = *(const f32x4*)src;
    f32x4 f1 = *(const f32x4*)(src + 4);
    ((short8*)w1s)[t] = cvt8(f0, f1);
}

typedef __attribute__((address_space(3))) void        lds_void;
typedef const __attribute__((address_space(1))) void  gm_void;

__device__ __forceinline__ void gload16(const void* g, void* l) {
    __builtin_amdgcn_global_load_lds((gm_void*)g, (lds_void*)l, 16, 0, 0);
}

// Main kernel: 4 waves x 16 rows = 64 rows/block, full K per block.
// x and W1-fragments staged into double-buffered LDS via global_load_lds;
// counted vmcnt(10) keeps next stage's loads in flight across barriers.
__global__ __launch_bounds__(256, 2)
void mlp_staged(const float* __restrict__ x,
                const float* __restrict__ b1,
                const float* __restrict__ W2,
                const float* __restrict__ b2,
                const unsigned short* __restrict__ w1s,
                float* __restrict__ out) {
    __shared__ __align__(16) unsigned char pool[2 * ABUF_SZ + 2 * BBUF_SZ]; // 80 KB

    const int tid = threadIdx.x;
    const int l   = tid & 63;          // lane
    const int w   = tid >> 6;          // wave (0..3)
    const int lr  = l & 15;            // A row within wave tile / C col
    const int kg  = l >> 4;            // k-group (0..3)
    const int rowbase = blockIdx.x * 64 + w * 16;

    char* ldsA = (char*)pool;                    // + buf*ABUF_SZ
    char* ldsB = (char*)pool + 2 * ABUF_SZ;      // + buf*BBUF_SZ

    const char* xw   = (const char*)x + (size_t)rowbase * ROWB;
    const char* wsrc = (const char*)w1s;
    const int   rpair = l >> 5;                  // 0/1: which row of the pair
    const int   pos   = (l & 31) * 16;           // byte pos within 512-B segment

    f32x4 acc0 = {0.f, 0.f, 0.f, 0.f};   // h cols 0..15
    f32x4 acc1 = {0.f, 0.f, 0.f, 0.f};   // h cols 16..31

    // stage t: per wave, 8 A-calls (own 16 rows x 512 B) + 2 B-calls = 10 vmem ops
    auto issue = [&](int t) {
        const int buf = t & 1;
        char* da = ldsA + buf * ABUF_SZ + w * 8192;
        const char* xs = xw + (size_t)t * 512 + (size_t)rpair * ROWB + pos;
        #pragma unroll
        for (int j = 0; j < 8; ++j)
            gload16(xs + (size_t)(2 * j) * ROWB, da + j * 1024);
        char* db = ldsB + buf * BBUF_SZ;
        #pragma unroll
        for (int c = 0; c < 2; ++c) {
            const int p = 2 * w + c;                   // (step s = p>>1, nt = p&1)
            const char* src = wsrc +
                ((size_t)((t * 4 + (p >> 1)) * 128 + (p & 1) * 64 + l)) * 16;
            gload16(src, db + p * 1024);
        }
    };

    auto compute = [&](int t) {
        const int buf = t & 1;
        const char* A = ldsA + buf * ABUF_SZ + w * 8192 + lr * 512 + kg * 32;
        const char* B = ldsB + buf * BBUF_SZ + l * 16;
        #pragma unroll
        for (int s = 0; s < 4; ++s) {
            f32x4 a0  = *(const f32x4*)(A + s * 128);
            f32x4 a1  = *(const f32x4*)(A + s * 128 + 16);
            short8 bf0 = *(const short8*)(B + (2 * s) * 1024);
            short8 bf1 = *(const short8*)(B + (2 * s + 1) * 1024);
            short8 af = cvt8(a0, a1);
            acc0 = __builtin_amdgcn_mfma_f32_16x16x32_bf16(af, bf0, acc0, 0, 0, 0);
            acc1 = __builtin_amdgcn_mfma_f32_16x16x32_bf16(af, bf1, acc1, 0, 0, 0);
        }
    };

    issue(0);
    #pragma unroll 1
    for (int t = 0; t < NSTAGE; ++t) {
        if (t + 1 < NSTAGE) {
            issue(t + 1);
            asm volatile("s_waitcnt vmcnt(10)" ::: "memory");  // stage t landed
        } else {
            asm volatile("s_waitcnt vmcnt(0)" ::: "memory");
        }
        __builtin_amdgcn_s_barrier();
        compute(t);
        asm volatile("" ::: "memory");
        __builtin_amdgcn_s_barrier();    // all waves done reading buf before overwrite
    }

    // epilogue: bias + relu -> per-wave h tile (alias staging pool, all reads done)
    float* hb = (float*)pool + w * (16 * 36);
    const float bv0 = b1[lr];
    const float bv1 = b1[lr + 16];
    #pragma unroll
    for (int i = 0; i < 4; ++i) {
        float v0 = acc0[i] + bv0; v0 = v0 > 0.f ? v0 : 0.f;
        float v1 = acc1[i] + bv1; v1 = v1 > 0.f ? v1 : 0.f;
        hb[(kg * 4 + i) * 36 + lr]      = v0;
        hb[(kg * 4 + i) * 36 + lr + 16] = v1;
    }
    __syncthreads();

    // layer 2: lanes 0..31; lane = half*16 + row
    if (l < 32) {
        const int half = l >> 4;
        const int row  = l & 15;
        f32x4 hv[8];
        const f32x4* hp = (const f32x4*)&hb[row * 36];
        #pragma unroll
        for (int q = 0; q < 8; ++q) hv[q] = hp[q];

        float* op = out + (size_t)(rowbase + row) * OUTS + half * 5;
        #pragma unroll
        for (int oo = 0; oo < 5; ++oo) {
            const int o = half * 5 + oo;
            const f32x4* w2p = (const f32x4*)(W2 + o * HIDDEN);
            f32x4 s4 = {0.f, 0.f, 0.f, 0.f};
            #pragma unroll
            for (int q = 0; q < 8; ++q) s4 += hv[q] * w2p[q];
            float v = b2[o] + s4[0] + s4[1] + s4[2] + s4[3];
            op[oo] = 1.0f / (1.0f + __expf(-v));
        }
    }
}

// Fallback (never expected to run: ws has always been large). fp32 W1 inline.
__global__ __launch_bounds__(256, 2)
void mlp_fallback(const float* __restrict__ x,
                  const float* __restrict__ W1,
                  const float* __restrict__ b1,
                  const float* __restrict__ W2,
                  const float* __restrict__ b2,
                  float* __restrict__ out) {
    __shared__ __align__(16) float hbuf[4][16][36];
    const int tid = threadIdx.x;
    const int l   = tid & 63;
    const int w   = tid >> 6;
    const int lr  = l & 15;
    const int kg  = l >> 4;
    const int rowbase = blockIdx.x * 64 + w * 16;

    const float* xp  = x + (size_t)(rowbase + lr) * IN_SIZE + kg * 8;
    const float* w0p = W1 + (size_t)lr * IN_SIZE + kg * 8;
    const float* w1p = W1 + (size_t)(lr + 16) * IN_SIZE + kg * 8;

    f32x4 acc0 = {0.f, 0.f, 0.f, 0.f};
    f32x4 acc1 = {0.f, 0.f, 0.f, 0.f};
    #pragma unroll 4
    for (int s = 0; s < IN_SIZE / 32; ++s) {
        f32x4 a0 = *(const f32x4*)(xp + s * 32);
        f32x4 a1 = *(const f32x4*)(xp + s * 32 + 4);
        f32x4 c0 = *(const f32x4*)(w0p + s * 32);
        f32x4 c1 = *(const f32x4*)(w0p + s * 32 + 4);
        f32x4 d0 = *(const f32x4*)(w1p + s * 32);
        f32x4 d1 = *(const f32x4*)(w1p + s * 32 + 4);
        short8 af  = cvt8(a0, a1);
        short8 bf0 = cvt8(c0, c1);
        short8 bf1 = cvt8(d0, d1);
        acc0 = __builtin_amdgcn_mfma_f32_16x16x32_bf16(af, bf0, acc0, 0, 0, 0);
        acc1 = __builtin_amdgcn_mfma_f32_16x16x32_bf16(af, bf1, acc1, 0, 0, 0);
    }
    const float bv0 = b1[lr];
    const float bv1 = b1[lr + 16];
    #pragma unroll
    for (int i = 0; i < 4; ++i) {
        float v0 = acc0[i] + bv0; v0 = v0 > 0.f ? v0 : 0.f;
        float v1 = acc1[i] + bv1; v1 = v1 > 0.f ? v1 : 0.f;
        hbuf[w][kg * 4 + i][lr]      = v0;
        hbuf[w][kg * 4 + i][lr + 16] = v1;
    }
    __syncthreads();
    if (l < 32) {
        const int half = l >> 4;
        const int row  = l & 15;
        f32x4 hv[8];
        const f32x4* hp = (const f32x4*)&hbuf[w][row][0];
        #pragma unroll
        for (int q = 0; q < 8; ++q) hv[q] = hp[q];
        float* op = out + (size_t)(rowbase + row) * OUTS + half * 5;
        #pragma unroll
        for (int oo = 0; oo < 5; ++oo) {
            const int o = half * 5 + oo;
            const f32x4* w2p = (const f32x4*)(W2 + o * HIDDEN);
            f32x4 s4 = {0.f, 0.f, 0.f, 0.f};
            #pragma unroll
            for (int q = 0; q < 8; ++q) s4 += hv[q] * w2p[q];
            float v = b2[o] + s4[0] + s4[1] + s4[2] + s4[3];
            op[oo] = 1.0f / (1.0f + __expf(-v));
        }
    }
}

extern "C" void kernel_launch(void* const* d_in, const int* in_sizes, int n_in,
                              void* d_out, int out_size, void* d_ws, size_t ws_size,
                              hipStream_t stream) {
    (void)n_in; (void)out_size;
    const float* x  = (const float*)d_in[0];
    const float* W1 = (const float*)d_in[1];
    const float* b1 = (const float*)d_in[2];
    const float* W2 = (const float*)d_in[3];
    const float* b2 = (const float*)d_in[4];
    float* out = (float*)d_out;

    const int N = in_sizes[0] / IN_SIZE;       // 32768
    const int nblocks = N / 64;                // 512

    const size_t ws_needed = (size_t)(IN_SIZE / 32) * 128 * 16;   // 196608 B
    if (ws_size >= ws_needed) {
        unsigned short* w1s = (unsigned short*)d_ws;
        prep_w1<<<dim3(48), dim3(256), 0, stream>>>(W1, w1s);
        mlp_staged<<<dim3(nblocks), dim3(256), 0, stream>>>(
            x, b1, W2, b2, w1s, out);
    } else {
        mlp_fallback<<<dim3(nblocks), dim3(256), 0, stream>>>(
            x, W1, b1, W2, b2, out);
    }
}